// Round 1
// baseline (178.757 us; speedup 1.0000x reference)
//
#include <hip/hip_runtime.h>
#include <hip/hip_bf16.h>

// SDPA forward: out = softmax(Q K^T / scale) V
// B=2,H=16 -> 32 batch-heads; S=2048; D=64. fp32 in/out.
// Flash-style: Q-tile 64 rows/block (4 waves x 16 rows), K-tile 64 keys.
// QK^T in split-bf16 (3 MFMA terms ~ fp32 precision), PV in bf16.

typedef __attribute__((ext_vector_type(8))) short bf16x8;
typedef __attribute__((ext_vector_type(4))) float f32x4;

#define MFMA16(a, b, c) __builtin_amdgcn_mfma_f32_16x16x32_bf16((a), (b), (c), 0, 0, 0)

constexpr int Sn = 2048;
constexpr int Dn = 64;
constexpr int QB = 64;   // q rows per block
constexpr int KB = 64;   // keys per tile
constexpr int BH = 32;   // B*H

__device__ __forceinline__ short f2bf(float x) {
    unsigned u = __builtin_bit_cast(unsigned, x);
    unsigned r = u + 0x7fffu + ((u >> 16) & 1u);   // RNE
    return (short)(r >> 16);
}
__device__ __forceinline__ float bf2f(short h) {
    unsigned u = ((unsigned)(unsigned short)h) << 16;
    return __builtin_bit_cast(float, u);
}

__global__ __launch_bounds__(256) void fattn(
    const float* __restrict__ Q, const float* __restrict__ K,
    const float* __restrict__ V, const float* __restrict__ scale_p,
    float* __restrict__ O)
{
    // LDS: Kh [64][64]bf16 (8KB) | Kl (8KB) | Vt[d=64][key=64]bf16 (8KB) | P 4x[16][64]bf16 (8KB)
    __shared__ __align__(16) char smem[32 * 1024];

    const int tid  = threadIdx.x;
    const int lane = tid & 63;
    const int wid  = tid >> 6;
    const int l15  = lane & 15;
    const int lgr  = lane >> 4;          // 0..3
    const int qtile = blockIdx.x;
    const int bh    = blockIdx.y;

    char* kh_b = smem;
    char* kl_b = smem + 8192;
    char* vt_b = smem + 16384;
    char* p_b  = smem + 24576 + wid * 2048;

    const float invs = 1.0f / scale_p[0];

    // ---- Q fragments (A-layout: row = lane&15, k = (lane>>4)*8 + j), pre-scaled by 1/scale ----
    const int q0 = qtile * QB + wid * 16;
    bf16x8 qh[2], ql[2];
    {
        const float* qrow = Q + ((size_t)bh * Sn + q0 + l15) * Dn;
#pragma unroll
        for (int ks = 0; ks < 2; ++ks) {
            const int d0 = ks * 32 + lgr * 8;
            f32x4 a = *(const f32x4*)(qrow + d0);
            f32x4 b = *(const f32x4*)(qrow + d0 + 4);
#pragma unroll
            for (int j = 0; j < 8; ++j) {
                float x = ((j < 4) ? a[j] : b[j - 4]) * invs;
                short h = f2bf(x);
                qh[ks][j] = h;
                ql[ks][j] = f2bf(x - bf2f(h));
            }
        }
    }

    f32x4 acc[4];
    float m_r[4], l_r[4];
#pragma unroll
    for (int i = 0; i < 4; ++i) {
        acc[i] = f32x4{0.f, 0.f, 0.f, 0.f};
        m_r[i] = -1e30f;
        l_r[i] = 0.f;
    }

    for (int kt = 0; kt < Sn / KB; ++kt) {
        const int k0 = kt * KB;

        // ---- stage K -> Kh/Kl (swizzled rows) ----
#pragma unroll
        for (int it = 0; it < 2; ++it) {
            const int c = tid + it * 256;       // 512 chunks: row = c>>3, d0 = (c&7)*8
            const int row = c >> 3;
            const int d0  = (c & 7) * 8;
            const float* gk = K + ((size_t)bh * Sn + k0 + row) * Dn + d0;
            f32x4 a = *(const f32x4*)gk;
            f32x4 b = *(const f32x4*)(gk + 4);
            bf16x8 hv, lv;
#pragma unroll
            for (int j = 0; j < 8; ++j) {
                float x = (j < 4) ? a[j] : b[j - 4];
                short h = f2bf(x);
                hv[j] = h;
                lv[j] = f2bf(x - bf2f(h));
            }
            const int off = (d0 * 2) ^ ((row & 7) << 4);
            *(bf16x8*)(kh_b + row * 128 + off) = hv;
            *(bf16x8*)(kl_b + row * 128 + off) = lv;
        }
        // ---- stage V transposed: Vt[d][key] (swizzled rows) ----
#pragma unroll
        for (int it = 0; it < 2; ++it) {
            const int c = tid + it * 256;       // 512 chunks: d = c>>3, keychunk = c&7
            const int d  = c >> 3;
            const int kc = c & 7;
            const float* gv = V + ((size_t)bh * Sn + k0 + kc * 8) * Dn + d;
            bf16x8 hv;
#pragma unroll
            for (int j = 0; j < 8; ++j) hv[j] = f2bf(gv[j * Dn]);
            const int off = (kc * 16) ^ ((d & 7) << 4);
            *(bf16x8*)(vt_b + d * 128 + off) = hv;
        }
        __syncthreads();

        // ---- QK^T: S = (Qh+Ql)(Kh+Kl)^T ~ QhKh + QhKl + QlKh ----
        f32x4 sc[4];
#pragma unroll
        for (int cb = 0; cb < 4; ++cb) sc[cb] = f32x4{0.f, 0.f, 0.f, 0.f};
#pragma unroll
        for (int ks = 0; ks < 2; ++ks) {
            const int koff = (ks * 32 + lgr * 8) * 2;
#pragma unroll
            for (int cb = 0; cb < 4; ++cb) {
                const int key = cb * 16 + l15;
                const int off = koff ^ ((key & 7) << 4);
                bf16x8 kbh = *(const bf16x8*)(kh_b + key * 128 + off);
                bf16x8 kbl = *(const bf16x8*)(kl_b + key * 128 + off);
                sc[cb] = MFMA16(qh[ks], kbh, sc[cb]);
                sc[cb] = MFMA16(ql[ks], kbh, sc[cb]);
                sc[cb] = MFMA16(qh[ks], kbl, sc[cb]);
            }
        }

        // ---- online softmax (C-layout: row = lgr*4+r, col = cb*16 + l15) ----
#pragma unroll
        for (int r = 0; r < 4; ++r) {
            float mx = fmaxf(fmaxf(sc[0][r], sc[1][r]), fmaxf(sc[2][r], sc[3][r]));
#pragma unroll
            for (int msk = 1; msk < 16; msk <<= 1)
                mx = fmaxf(mx, __shfl_xor(mx, msk));
            const float mnew = fmaxf(m_r[r], mx);
            const float fac  = __expf(m_r[r] - mnew);
            m_r[r] = mnew;
            const int prow = lgr * 4 + r;
            const int pswz = (prow & 7) << 4;
            char* prowp = p_b + prow * 128;
            float rsum = 0.f;
#pragma unroll
            for (int cb = 0; cb < 4; ++cb) {
                float p = __expf(sc[cb][r] - mnew);
                short pb = f2bf(p);
                rsum += bf2f(pb);   // denominator from ROUNDED p: cancels P-rounding bias
                const int colb = (cb * 16 + l15) * 2;
                *(short*)(prowp + (colb ^ pswz)) = pb;
            }
#pragma unroll
            for (int msk = 1; msk < 16; msk <<= 1)
                rsum += __shfl_xor(rsum, msk);
            l_r[r] = l_r[r] * fac + rsum;
#pragma unroll
            for (int dcb = 0; dcb < 4; ++dcb) acc[dcb][r] *= fac;
        }

        // ---- PV: A = P (wave-private LDS), B = Vt rows ----
#pragma unroll
        for (int kc = 0; kc < 2; ++kc) {
            const int poff = ((kc * 32 + lgr * 8) * 2) ^ ((l15 & 7) << 4);
            bf16x8 pa = *(const bf16x8*)(p_b + l15 * 128 + poff);
            const int koff2 = (kc * 32 + lgr * 8) * 2;
#pragma unroll
            for (int dcb = 0; dcb < 4; ++dcb) {
                const int vrow = dcb * 16 + l15;
                const int voff = koff2 ^ ((vrow & 7) << 4);
                bf16x8 vb = *(const bf16x8*)(vt_b + vrow * 128 + voff);
                acc[dcb] = MFMA16(pa, vb, acc[dcb]);
            }
        }
        __syncthreads();
    }

    // ---- epilogue: out = acc / l ----
#pragma unroll
    for (int r = 0; r < 4; ++r) {
        const int qrow = q0 + lgr * 4 + r;
        const float inv_l = 1.0f / l_r[r];
        float* orow = O + ((size_t)bh * Sn + qrow) * Dn;
#pragma unroll
        for (int dcb = 0; dcb < 4; ++dcb)
            orow[dcb * 16 + l15] = acc[dcb][r] * inv_l;
    }
}

extern "C" void kernel_launch(void* const* d_in, const int* in_sizes, int n_in,
                              void* d_out, int out_size, void* d_ws, size_t ws_size,
                              hipStream_t stream) {
    const float* Q = (const float*)d_in[0];
    const float* K = (const float*)d_in[1];
    const float* V = (const float*)d_in[2];
    const float* scale_p = (const float*)d_in[3];
    float* O = (float*)d_out;

    dim3 grid(Sn / QB, BH);   // 32 q-tiles x 32 batch-heads = 1024 blocks
    fattn<<<grid, 256, 0, stream>>>(Q, K, V, scale_p, O);
}

// Round 2
// 162.678 us; speedup vs baseline: 1.0988x; 1.0988x over previous
//
#include <hip/hip_runtime.h>
#include <hip/hip_bf16.h>

// SDPA forward: out = softmax(Q K^T / scale) V ; B=2,H=16,S=2048,D=64, fp32 io.
// R2: pre-pass converts K -> (Kh,Kl) split-bf16 and V -> Vt (transposed) bf16,
// stored as pre-swizzled 8KB LDS tile images in d_ws. Main kernel stages them
// with global_load_lds (width 16) + 2-phase double-buffer prefetch.
// QK^T = QhKh + QlKh + QhKl (~fp32 precision); PV bf16.

typedef __attribute__((ext_vector_type(8))) short bf16x8;
typedef __attribute__((ext_vector_type(4))) float f32x4;
typedef __attribute__((address_space(3))) unsigned int lds_u32;
typedef __attribute__((address_space(1))) const unsigned int glb_u32;

#define MFMA16(a, b, c) __builtin_amdgcn_mfma_f32_16x16x32_bf16((a), (b), (c), 0, 0, 0)

constexpr int Sn = 2048;
constexpr int Dn = 64;
constexpr int QB = 64;   // q rows per block
constexpr int KB = 64;   // keys per tile
constexpr int BH = 32;   // B*H
constexpr int NT = Sn / KB;              // 32 k-tiles
constexpr size_t TILE_B = 8192;          // one tile image (64x64 bf16)
constexpr size_t ARR_B  = (size_t)BH * NT * TILE_B;   // 8 MB per array
constexpr size_t WS_NEED = 3 * ARR_B;                 // 24 MB

__device__ __forceinline__ short f2bf(float x) {
    unsigned u = __builtin_bit_cast(unsigned, x);
    unsigned r = u + 0x7fffu + ((u >> 16) & 1u);   // RNE
    return (short)(r >> 16);
}
__device__ __forceinline__ float bf2f(short h) {
    unsigned u = ((unsigned)(unsigned short)h) << 16;
    return __builtin_bit_cast(float, u);
}

// ---------------- pre-pass: build swizzled bf16 tile images ----------------
__global__ __launch_bounds__(256) void prep(
    const float* __restrict__ K, const float* __restrict__ V,
    char* __restrict__ kh_g, char* __restrict__ kl_g, char* __restrict__ vt_g)
{
    const int tid = threadIdx.x;
    const int kt  = blockIdx.x;
    const int bh  = blockIdx.y;
    const int k0  = kt * KB;
    const size_t tbase = ((size_t)bh * NT + kt) * TILE_B;

    // K -> Kh/Kl, row-major [key][d], rows XOR-swizzled
#pragma unroll
    for (int it = 0; it < 2; ++it) {
        const int c   = tid + it * 256;
        const int row = c >> 3;
        const int d0  = (c & 7) * 8;
        const float* gk = K + ((size_t)bh * Sn + k0 + row) * Dn + d0;
        f32x4 a = *(const f32x4*)gk;
        f32x4 b = *(const f32x4*)(gk + 4);
        bf16x8 hv, lv;
#pragma unroll
        for (int j = 0; j < 8; ++j) {
            float x = (j < 4) ? a[j] : b[j - 4];
            short h = f2bf(x);
            hv[j] = h;
            lv[j] = f2bf(x - bf2f(h));
        }
        const int off = (d0 * 2) ^ ((row & 7) << 4);
        *(bf16x8*)(kh_g + tbase + row * 128 + off) = hv;
        *(bf16x8*)(kl_g + tbase + row * 128 + off) = lv;
    }
    // V -> Vt[d][key], rows XOR-swizzled (transpose paid once here)
#pragma unroll
    for (int it = 0; it < 2; ++it) {
        const int c  = tid + it * 256;
        const int d  = c >> 3;
        const int kc = c & 7;
        const float* gv = V + ((size_t)bh * Sn + k0 + kc * 8) * Dn + d;
        bf16x8 hv;
#pragma unroll
        for (int j = 0; j < 8; ++j) hv[j] = f2bf(gv[j * Dn]);
        const int off = (kc * 16) ^ ((d & 7) << 4);
        *(bf16x8*)(vt_g + tbase + d * 128 + off) = hv;
    }
}

// ---------------- main flash kernel ----------------
__device__ __forceinline__ void stage_buf(const char* g, char* l, int wid, int lane) {
    // 8KB buffer: 2 rounds x 4 waves x 64 lanes x 16B (linear; source pre-swizzled)
#pragma unroll
    for (int r = 0; r < 2; ++r) {
        const int off = r * 4096 + wid * 1024;
        __builtin_amdgcn_global_load_lds((glb_u32*)(g + off + lane * 16),
                                         (lds_u32*)(l + off), 16, 0, 0);
    }
}

__global__ __launch_bounds__(256) void fattn2(
    const float* __restrict__ Q,
    const char* __restrict__ kh_g, const char* __restrict__ kl_g,
    const char* __restrict__ vt_g,
    const float* __restrict__ scale_p, float* __restrict__ O)
{
    // LDS: 2 stage buffers x (Kh 8K | Kl 8K | Vt 8K) = 48K, P 4x2K = 8K
    __shared__ __align__(16) char smem[56 * 1024];

    const int tid  = threadIdx.x;
    const int lane = tid & 63;
    const int wid  = tid >> 6;
    const int l15  = lane & 15;
    const int lgr  = lane >> 4;
    const int qtile = blockIdx.x;
    const int bh    = blockIdx.y;

    char* p_b = smem + 49152 + wid * 2048;
    const char* khg = kh_g + (size_t)bh * NT * TILE_B;
    const char* klg = kl_g + (size_t)bh * NT * TILE_B;
    const char* vtg = vt_g + (size_t)bh * NT * TILE_B;

    const float invs = 1.0f / scale_p[0];

    // Q fragments (A-layout: row = lane&15, k = (lane>>4)*8 + j), pre-scaled
    const int q0 = qtile * QB + wid * 16;
    bf16x8 qh[2], ql[2];
    {
        const float* qrow = Q + ((size_t)bh * Sn + q0 + l15) * Dn;
#pragma unroll
        for (int ks = 0; ks < 2; ++ks) {
            const int d0 = ks * 32 + lgr * 8;
            f32x4 a = *(const f32x4*)(qrow + d0);
            f32x4 b = *(const f32x4*)(qrow + d0 + 4);
#pragma unroll
            for (int j = 0; j < 8; ++j) {
                float x = ((j < 4) ? a[j] : b[j - 4]) * invs;
                short h = f2bf(x);
                qh[ks][j] = h;
                ql[ks][j] = f2bf(x - bf2f(h));
            }
        }
    }

    f32x4 acc[4];
    float m_r[4], l_r[4];
#pragma unroll
    for (int i = 0; i < 4; ++i) {
        acc[i] = f32x4{0.f, 0.f, 0.f, 0.f};
        m_r[i] = -1e30f;
        l_r[i] = 0.f;
    }

    // prologue: stage tile 0 into buf0
    stage_buf(khg, smem + 0,     wid, lane);
    stage_buf(klg, smem + 8192,  wid, lane);
    stage_buf(vtg, smem + 16384, wid, lane);
    asm volatile("s_waitcnt vmcnt(0)" ::: "memory");
    __syncthreads();

    int cur = 0;
    for (int kt = 0; kt < NT; ++kt) {
        // prefetch next tile into the other buffer (overlaps with compute)
        if (kt + 1 < NT) {
            char* nb = smem + (cur ^ 1) * 24576;
            const size_t toff = (size_t)(kt + 1) * TILE_B;
            stage_buf(khg + toff, nb,         wid, lane);
            stage_buf(klg + toff, nb + 8192,  wid, lane);
            stage_buf(vtg + toff, nb + 16384, wid, lane);
        }

        char* kh_b = smem + cur * 24576;
        char* kl_b = kh_b + 8192;
        char* vt_b = kh_b + 16384;

        // ---- QK^T: S ~ QhKh + QlKh + QhKl ----
        f32x4 sc[4];
#pragma unroll
        for (int cb = 0; cb < 4; ++cb) sc[cb] = f32x4{0.f, 0.f, 0.f, 0.f};
        __builtin_amdgcn_s_setprio(1);
#pragma unroll
        for (int ks = 0; ks < 2; ++ks) {
            const int koff = (ks * 32 + lgr * 8) * 2;
#pragma unroll
            for (int cb = 0; cb < 4; ++cb) {
                const int key = cb * 16 + l15;
                const int off = koff ^ ((key & 7) << 4);
                bf16x8 kbh = *(const bf16x8*)(kh_b + key * 128 + off);
                bf16x8 kbl = *(const bf16x8*)(kl_b + key * 128 + off);
                sc[cb] = MFMA16(qh[ks], kbh, sc[cb]);
                sc[cb] = MFMA16(ql[ks], kbh, sc[cb]);
                sc[cb] = MFMA16(qh[ks], kbl, sc[cb]);
            }
        }
        __builtin_amdgcn_s_setprio(0);

        // ---- online softmax (C-layout: row = lgr*4+r, col = cb*16+l15) ----
#pragma unroll
        for (int r = 0; r < 4; ++r) {
            float mx = fmaxf(fmaxf(sc[0][r], sc[1][r]), fmaxf(sc[2][r], sc[3][r]));
#pragma unroll
            for (int msk = 1; msk < 16; msk <<= 1)
                mx = fmaxf(mx, __shfl_xor(mx, msk));
            const float mnew = fmaxf(m_r[r], mx);
            const float fac  = __expf(m_r[r] - mnew);
            m_r[r] = mnew;
            const int prow = lgr * 4 + r;
            const int pswz = (prow & 7) << 4;
            char* prowp = p_b + prow * 128;
            float rsum = 0.f;
#pragma unroll
            for (int cb = 0; cb < 4; ++cb) {
                float p = __expf(sc[cb][r] - mnew);
                short pb = f2bf(p);
                rsum += bf2f(pb);   // denominator from ROUNDED p
                const int colb = (cb * 16 + l15) * 2;
                *(short*)(prowp + (colb ^ pswz)) = pb;
            }
#pragma unroll
            for (int msk = 1; msk < 16; msk <<= 1)
                rsum += __shfl_xor(rsum, msk);
            l_r[r] = l_r[r] * fac + rsum;
#pragma unroll
            for (int dcb = 0; dcb < 4; ++dcb) acc[dcb][r] *= fac;
        }

        // ---- PV: A = P (wave-private LDS), B = Vt rows ----
        __builtin_amdgcn_s_setprio(1);
#pragma unroll
        for (int kc = 0; kc < 2; ++kc) {
            const int poff = ((kc * 32 + lgr * 8) * 2) ^ ((l15 & 7) << 4);
            bf16x8 pa = *(const bf16x8*)(p_b + l15 * 128 + poff);
            const int koff2 = (kc * 32 + lgr * 8) * 2;
#pragma unroll
            for (int dcb = 0; dcb < 4; ++dcb) {
                const int vrow = dcb * 16 + l15;
                const int voff = koff2 ^ ((vrow & 7) << 4);
                bf16x8 vb = *(const bf16x8*)(vt_b + vrow * 128 + voff);
                acc[dcb] = MFMA16(pa, vb, acc[dcb]);
            }
        }
        __builtin_amdgcn_s_setprio(0);

        // drain prefetch, flip buffers
        asm volatile("s_waitcnt vmcnt(0)" ::: "memory");
        __syncthreads();
        cur ^= 1;
    }

    // ---- epilogue ----
#pragma unroll
    for (int r = 0; r < 4; ++r) {
        const int qrow = q0 + lgr * 4 + r;
        const float inv_l = 1.0f / l_r[r];
        float* orow = O + ((size_t)bh * Sn + qrow) * Dn;
#pragma unroll
        for (int dcb = 0; dcb < 4; ++dcb)
            orow[dcb * 16 + l15] = acc[dcb][r] * inv_l;
    }
}

// ---------------- fallback (R1 kernel, used if ws too small) ----------------
__global__ __launch_bounds__(256) void fattn_fb(
    const float* __restrict__ Q, const float* __restrict__ K,
    const float* __restrict__ V, const float* __restrict__ scale_p,
    float* __restrict__ O)
{
    __shared__ __align__(16) char smem[32 * 1024];
    const int tid  = threadIdx.x;
    const int lane = tid & 63;
    const int wid  = tid >> 6;
    const int l15  = lane & 15;
    const int lgr  = lane >> 4;
    const int qtile = blockIdx.x;
    const int bh    = blockIdx.y;
    char* kh_b = smem;
    char* kl_b = smem + 8192;
    char* vt_b = smem + 16384;
    char* p_b  = smem + 24576 + wid * 2048;
    const float invs = 1.0f / scale_p[0];
    const int q0 = qtile * QB + wid * 16;
    bf16x8 qh[2], ql[2];
    {
        const float* qrow = Q + ((size_t)bh * Sn + q0 + l15) * Dn;
#pragma unroll
        for (int ks = 0; ks < 2; ++ks) {
            const int d0 = ks * 32 + lgr * 8;
            f32x4 a = *(const f32x4*)(qrow + d0);
            f32x4 b = *(const f32x4*)(qrow + d0 + 4);
#pragma unroll
            for (int j = 0; j < 8; ++j) {
                float x = ((j < 4) ? a[j] : b[j - 4]) * invs;
                short h = f2bf(x);
                qh[ks][j] = h;
                ql[ks][j] = f2bf(x - bf2f(h));
            }
        }
    }
    f32x4 acc[4];
    float m_r[4], l_r[4];
#pragma unroll
    for (int i = 0; i < 4; ++i) {
        acc[i] = f32x4{0.f, 0.f, 0.f, 0.f};
        m_r[i] = -1e30f; l_r[i] = 0.f;
    }
    for (int kt = 0; kt < NT; ++kt) {
        const int k0 = kt * KB;
#pragma unroll
        for (int it = 0; it < 2; ++it) {
            const int c = tid + it * 256;
            const int row = c >> 3;
            const int d0  = (c & 7) * 8;
            const float* gk = K + ((size_t)bh * Sn + k0 + row) * Dn + d0;
            f32x4 a = *(const f32x4*)gk;
            f32x4 b = *(const f32x4*)(gk + 4);
            bf16x8 hv, lv;
#pragma unroll
            for (int j = 0; j < 8; ++j) {
                float x = (j < 4) ? a[j] : b[j - 4];
                short h = f2bf(x);
                hv[j] = h; lv[j] = f2bf(x - bf2f(h));
            }
            const int off = (d0 * 2) ^ ((row & 7) << 4);
            *(bf16x8*)(kh_b + row * 128 + off) = hv;
            *(bf16x8*)(kl_b + row * 128 + off) = lv;
        }
#pragma unroll
        for (int it = 0; it < 2; ++it) {
            const int c = tid + it * 256;
            const int d  = c >> 3;
            const int kc = c & 7;
            const float* gv = V + ((size_t)bh * Sn + k0 + kc * 8) * Dn + d;
            bf16x8 hv;
#pragma unroll
            for (int j = 0; j < 8; ++j) hv[j] = f2bf(gv[j * Dn]);
            const int off = (kc * 16) ^ ((d & 7) << 4);
            *(bf16x8*)(vt_b + d * 128 + off) = hv;
        }
        __syncthreads();
        f32x4 sc[4];
#pragma unroll
        for (int cb = 0; cb < 4; ++cb) sc[cb] = f32x4{0.f, 0.f, 0.f, 0.f};
#pragma unroll
        for (int ks = 0; ks < 2; ++ks) {
            const int koff = (ks * 32 + lgr * 8) * 2;
#pragma unroll
            for (int cb = 0; cb < 4; ++cb) {
                const int key = cb * 16 + l15;
                const int off = koff ^ ((key & 7) << 4);
                bf16x8 kbh = *(const bf16x8*)(kh_b + key * 128 + off);
                bf16x8 kbl = *(const bf16x8*)(kl_b + key * 128 + off);
                sc[cb] = MFMA16(qh[ks], kbh, sc[cb]);
                sc[cb] = MFMA16(ql[ks], kbh, sc[cb]);
                sc[cb] = MFMA16(qh[ks], kbl, sc[cb]);
            }
        }
#pragma unroll
        for (int r = 0; r < 4; ++r) {
            float mx = fmaxf(fmaxf(sc[0][r], sc[1][r]), fmaxf(sc[2][r], sc[3][r]));
#pragma unroll
            for (int msk = 1; msk < 16; msk <<= 1)
                mx = fmaxf(mx, __shfl_xor(mx, msk));
            const float mnew = fmaxf(m_r[r], mx);
            const float fac  = __expf(m_r[r] - mnew);
            m_r[r] = mnew;
            const int prow = lgr * 4 + r;
            const int pswz = (prow & 7) << 4;
            char* prowp = p_b + prow * 128;
            float rsum = 0.f;
#pragma unroll
            for (int cb = 0; cb < 4; ++cb) {
                float p = __expf(sc[cb][r] - mnew);
                short pb = f2bf(p);
                rsum += bf2f(pb);
                const int colb = (cb * 16 + l15) * 2;
                *(short*)(prowp + (colb ^ pswz)) = pb;
            }
#pragma unroll
            for (int msk = 1; msk < 16; msk <<= 1)
                rsum += __shfl_xor(rsum, msk);
            l_r[r] = l_r[r] * fac + rsum;
#pragma unroll
            for (int dcb = 0; dcb < 4; ++dcb) acc[dcb][r] *= fac;
        }
#pragma unroll
        for (int kc = 0; kc < 2; ++kc) {
            const int poff = ((kc * 32 + lgr * 8) * 2) ^ ((l15 & 7) << 4);
            bf16x8 pa = *(const bf16x8*)(p_b + l15 * 128 + poff);
            const int koff2 = (kc * 32 + lgr * 8) * 2;
#pragma unroll
            for (int dcb = 0; dcb < 4; ++dcb) {
                const int vrow = dcb * 16 + l15;
                const int voff = koff2 ^ ((vrow & 7) << 4);
                bf16x8 vb = *(const bf16x8*)(vt_b + vrow * 128 + voff);
                acc[dcb] = MFMA16(pa, vb, acc[dcb]);
            }
        }
        __syncthreads();
    }
#pragma unroll
    for (int r = 0; r < 4; ++r) {
        const int qrow = q0 + lgr * 4 + r;
        const float inv_l = 1.0f / l_r[r];
        float* orow = O + ((size_t)bh * Sn + qrow) * Dn;
#pragma unroll
        for (int dcb = 0; dcb < 4; ++dcb)
            orow[dcb * 16 + l15] = acc[dcb][r] * inv_l;
    }
}

extern "C" void kernel_launch(void* const* d_in, const int* in_sizes, int n_in,
                              void* d_out, int out_size, void* d_ws, size_t ws_size,
                              hipStream_t stream) {
    const float* Q = (const float*)d_in[0];
    const float* K = (const float*)d_in[1];
    const float* V = (const float*)d_in[2];
    const float* scale_p = (const float*)d_in[3];
    float* O = (float*)d_out;

    if (ws_size >= WS_NEED) {
        char* kh_g = (char*)d_ws;
        char* kl_g = kh_g + ARR_B;
        char* vt_g = kl_g + ARR_B;
        dim3 pgrid(NT, BH);
        prep<<<pgrid, 256, 0, stream>>>(K, V, kh_g, kl_g, vt_g);
        dim3 grid(Sn / QB, BH);
        fattn2<<<grid, 256, 0, stream>>>(Q, kh_g, kl_g, vt_g, scale_p, O);
    } else {
        dim3 grid(Sn / QB, BH);
        fattn_fb<<<grid, 256, 0, stream>>>(Q, K, V, scale_p, O);
    }
}

// Round 3
// 97.575 us; speedup vs baseline: 1.8320x; 1.6672x over previous
//
#include <hip/hip_runtime.h>
#include <hip/hip_bf16.h>

// SDPA forward: out = softmax(Q K^T / scale) V ; B=2,H=16,S=2048,D=64, fp32 io.
// R3: swapped QK^T (mfma(K,Q) -> S^T[key][q], lane-local q-row softmax),
// QB=128 / 512 threads (16 waves/CU), pre-pass bf16 split images in d_ws,
// global_load_lds staging + 2-phase double buffer.
// QK^T = KhQh + KhQl + KlQh (~fp32 precision); PV bf16.

typedef __attribute__((ext_vector_type(8))) short bf16x8;
typedef __attribute__((ext_vector_type(4))) float f32x4;
typedef __attribute__((address_space(3))) unsigned int lds_u32;
typedef __attribute__((address_space(1))) const unsigned int glb_u32;

#define MFMA16(a, b, c) __builtin_amdgcn_mfma_f32_16x16x32_bf16((a), (b), (c), 0, 0, 0)

constexpr int Sn = 2048;
constexpr int Dn = 64;
constexpr int QB = 128;  // q rows per block (8 waves x 16)
constexpr int KB = 64;   // keys per tile
constexpr int BH = 32;   // B*H
constexpr int NT = Sn / KB;              // 32 k-tiles
constexpr size_t TILE_B = 8192;          // one tile image (64x64 bf16)
constexpr size_t ARR_B  = (size_t)BH * NT * TILE_B;   // 8 MB per array
constexpr size_t WS_NEED = 3 * ARR_B;                 // 24 MB

__device__ __forceinline__ short f2bf(float x) {
    unsigned u = __builtin_bit_cast(unsigned, x);
    unsigned r = u + 0x7fffu + ((u >> 16) & 1u);   // RNE
    return (short)(r >> 16);
}
__device__ __forceinline__ float bf2f(short h) {
    unsigned u = ((unsigned)(unsigned short)h) << 16;
    return __builtin_bit_cast(float, u);
}
__device__ __forceinline__ unsigned cvt_pk_bf16(float lo, float hi) {
    unsigned r;
    asm("v_cvt_pk_bf16_f32 %0, %1, %2" : "=v"(r) : "v"(lo), "v"(hi));
    return r;
}

// ---------------- pre-pass: build swizzled bf16 tile images ----------------
__global__ __launch_bounds__(256) void prep(
    const float* __restrict__ K, const float* __restrict__ V,
    char* __restrict__ kh_g, char* __restrict__ kl_g, char* __restrict__ vt_g)
{
    const int tid = threadIdx.x;
    const int kt  = blockIdx.x;
    const int bh  = blockIdx.y;
    const int k0  = kt * KB;
    const size_t tbase = ((size_t)bh * NT + kt) * TILE_B;

    // K -> Kh/Kl, row-major [key][d], rows XOR-swizzled
#pragma unroll
    for (int it = 0; it < 2; ++it) {
        const int c   = tid + it * 256;
        const int row = c >> 3;
        const int d0  = (c & 7) * 8;
        const float* gk = K + ((size_t)bh * Sn + k0 + row) * Dn + d0;
        f32x4 a = *(const f32x4*)gk;
        f32x4 b = *(const f32x4*)(gk + 4);
        bf16x8 hv, lv;
#pragma unroll
        for (int j = 0; j < 8; ++j) {
            float x = (j < 4) ? a[j] : b[j - 4];
            short h = f2bf(x);
            hv[j] = h;
            lv[j] = f2bf(x - bf2f(h));
        }
        const int off = (d0 * 2) ^ ((row & 7) << 4);
        *(bf16x8*)(kh_g + tbase + row * 128 + off) = hv;
        *(bf16x8*)(kl_g + tbase + row * 128 + off) = lv;
    }
    // V -> Vt[d][key], rows XOR-swizzled (transpose paid once here)
#pragma unroll
    for (int it = 0; it < 2; ++it) {
        const int c  = tid + it * 256;
        const int d  = c >> 3;
        const int kc = c & 7;
        const float* gv = V + ((size_t)bh * Sn + k0 + kc * 8) * Dn + d;
        bf16x8 hv;
#pragma unroll
        for (int j = 0; j < 8; ++j) hv[j] = f2bf(gv[j * Dn]);
        const int off = (kc * 16) ^ ((d & 7) << 4);
        *(bf16x8*)(vt_g + tbase + d * 128 + off) = hv;
    }
}

// ---------------- main flash kernel (512 threads, QB=128) ----------------
__device__ __forceinline__ void stage(const char* g, char* l, int wid, int lane) {
    // 8KB: 8 waves x 64 lanes x 16B (linear dest; source pre-swizzled)
    const int off = wid * 1024;
    __builtin_amdgcn_global_load_lds((glb_u32*)(g + off + lane * 16),
                                     (lds_u32*)(l + off), 16, 0, 0);
}

__global__ __launch_bounds__(512, 4) void fattn3(
    const float* __restrict__ Q,
    const char* __restrict__ kh_g, const char* __restrict__ kl_g,
    const char* __restrict__ vt_g,
    const float* __restrict__ scale_p, float* __restrict__ O)
{
    // LDS: 2 x (Kh 8K | Kl 8K | Vt 8K) = 48K, P 8 x 2K = 16K -> 64K
    __shared__ __align__(16) char smem[64 * 1024];

    const int tid  = threadIdx.x;
    const int lane = tid & 63;
    const int wid  = tid >> 6;          // 0..7
    const int l15  = lane & 15;
    const int lgr  = lane >> 4;         // 0..3
    const int qtile = blockIdx.x;
    const int bh    = blockIdx.y;

    char* p_b = smem + 49152 + wid * 2048;
    const char* khg = kh_g + (size_t)bh * NT * TILE_B;
    const char* klg = kl_g + (size_t)bh * NT * TILE_B;
    const char* vtg = vt_g + (size_t)bh * NT * TILE_B;

    const float invs = 1.0f / scale_p[0];

    // Q fragments (B-operand layout == A layout: n=lane&15, k=lgr*8+j), pre-scaled
    const int q0 = qtile * QB + wid * 16;
    bf16x8 qh[2], ql[2];
    {
        const float* qrow = Q + ((size_t)bh * Sn + q0 + l15) * Dn;
#pragma unroll
        for (int ks = 0; ks < 2; ++ks) {
            const int d0 = ks * 32 + lgr * 8;
            f32x4 a = *(const f32x4*)(qrow + d0);
            f32x4 b = *(const f32x4*)(qrow + d0 + 4);
#pragma unroll
            for (int j = 0; j < 8; ++j) {
                float x = ((j < 4) ? a[j] : b[j - 4]) * invs;
                short h = f2bf(x);
                qh[ks][j] = h;
                ql[ks][j] = f2bf(x - bf2f(h));
            }
        }
    }

    f32x4 acc[4];
#pragma unroll
    for (int i = 0; i < 4; ++i) acc[i] = f32x4{0.f, 0.f, 0.f, 0.f};
    float m1 = -1e30f, l1 = 0.f;   // stats for q = l15 (jointly across lgr groups)

    // prologue: stage tile 0 into buf0
    stage(khg, smem + 0,     wid, lane);
    stage(klg, smem + 8192,  wid, lane);
    stage(vtg, smem + 16384, wid, lane);
    asm volatile("s_waitcnt vmcnt(0)" ::: "memory");
    __syncthreads();

    int cur = 0;
    for (int kt = 0; kt < NT; ++kt) {
        if (kt + 1 < NT) {
            char* nb = smem + (cur ^ 1) * 24576;
            const size_t toff = (size_t)(kt + 1) * TILE_B;
            stage(khg + toff, nb,         wid, lane);
            stage(klg + toff, nb + 8192,  wid, lane);
            stage(vtg + toff, nb + 16384, wid, lane);
        }

        char* kh_b = smem + cur * 24576;
        char* kl_b = kh_b + 8192;
        char* vt_b = kh_b + 16384;

        // ---- swapped QK^T: S^T[key][q] = (Kh+Kl)(Qh+Ql)^T ~ KhQh + KhQl + KlQh ----
        f32x4 sc[4];
#pragma unroll
        for (int cb = 0; cb < 4; ++cb) sc[cb] = f32x4{0.f, 0.f, 0.f, 0.f};
        __builtin_amdgcn_s_setprio(1);
#pragma unroll
        for (int ks = 0; ks < 2; ++ks) {
            const int koff = (ks * 32 + lgr * 8) * 2;
#pragma unroll
            for (int cb = 0; cb < 4; ++cb) {
                const int key = cb * 16 + l15;
                const int off = koff ^ ((key & 7) << 4);
                bf16x8 kbh = *(const bf16x8*)(kh_b + key * 128 + off);
                bf16x8 kbl = *(const bf16x8*)(kl_b + key * 128 + off);
                sc[cb] = MFMA16(kbh, qh[ks], sc[cb]);
                sc[cb] = MFMA16(kbh, ql[ks], sc[cb]);
                sc[cb] = MFMA16(kbl, qh[ks], sc[cb]);
            }
        }
        __builtin_amdgcn_s_setprio(0);

        // ---- lane-local softmax: lane holds S^T[cb*16+lgr*4+r][q=l15] ----
        float mx = -1e30f;
#pragma unroll
        for (int cb = 0; cb < 4; ++cb)
#pragma unroll
            for (int r = 0; r < 4; ++r) mx = fmaxf(mx, sc[cb][r]);
        mx = fmaxf(mx, __shfl_xor(mx, 16));
        mx = fmaxf(mx, __shfl_xor(mx, 32));
        const float mnew = fmaxf(m1, mx);
        const float fac  = __expf(m1 - mnew);
        m1 = mnew;

        unsigned pw[4][2];
        float rsum = 0.f;
#pragma unroll
        for (int cb = 0; cb < 4; ++cb) {
            float p0 = __expf(sc[cb][0] - mnew);
            float p1 = __expf(sc[cb][1] - mnew);
            float p2 = __expf(sc[cb][2] - mnew);
            float p3 = __expf(sc[cb][3] - mnew);
            pw[cb][0] = cvt_pk_bf16(p0, p1);
            pw[cb][1] = cvt_pk_bf16(p2, p3);
            // denominator from ROUNDED p (cancels P rounding bias)
#pragma unroll
            for (int d2 = 0; d2 < 2; ++d2) {
                rsum += __builtin_bit_cast(float, pw[cb][d2] << 16);
                rsum += __builtin_bit_cast(float, pw[cb][d2] & 0xffff0000u);
            }
        }
        rsum += __shfl_xor(rsum, 16);
        rsum += __shfl_xor(rsum, 32);
        l1 = l1 * fac + rsum;

        // ---- write P[q][key] (wave-private, swizzled rows): 4 x ds_write_b64 ----
        {
            const int pswz = (l15 & 7) << 4;
            char* prow = p_b + l15 * 128;
#pragma unroll
            for (int cb = 0; cb < 4; ++cb) {
                unsigned long long v =
                    (unsigned long long)pw[cb][0] |
                    ((unsigned long long)pw[cb][1] << 32);
                *(unsigned long long*)(prow + ((cb * 32 + lgr * 8) ^ pswz)) = v;
            }
        }

        // ---- rescale acc rows (C rows are q = lgr*4+r; fac lives at lane l15=q) ----
#pragma unroll
        for (int r = 0; r < 4; ++r) {
            const float facr = __shfl(fac, (lane & 48) | (lgr * 4 + r));
#pragma unroll
            for (int dcb = 0; dcb < 4; ++dcb) acc[dcb][r] *= facr;
        }

        // ---- PV: A = P (wave-private LDS), B = Vt rows ----
        __builtin_amdgcn_s_setprio(1);
#pragma unroll
        for (int ks = 0; ks < 2; ++ks) {
            const int koff2 = ks * 64 + lgr * 16;
            const int poff  = koff2 ^ ((l15 & 7) << 4);
            bf16x8 pa = *(const bf16x8*)(p_b + l15 * 128 + poff);
#pragma unroll
            for (int dcb = 0; dcb < 4; ++dcb) {
                const int vrow = dcb * 16 + l15;
                const int voff = koff2 ^ ((vrow & 7) << 4);
                bf16x8 vb = *(const bf16x8*)(vt_b + vrow * 128 + voff);
                acc[dcb] = MFMA16(pa, vb, acc[dcb]);
            }
        }
        __builtin_amdgcn_s_setprio(0);

        asm volatile("s_waitcnt vmcnt(0)" ::: "memory");
        __syncthreads();
        cur ^= 1;
    }

    // ---- epilogue: out = acc / l (inv_l lives at lane l15=q, broadcast per row) ----
    const float invl = 1.0f / l1;
#pragma unroll
    for (int r = 0; r < 4; ++r) {
        const float invr = __shfl(invl, (lane & 48) | (lgr * 4 + r));
        const int qrow = q0 + lgr * 4 + r;
        float* orow = O + ((size_t)bh * Sn + qrow) * Dn;
#pragma unroll
        for (int dcb = 0; dcb < 4; ++dcb)
            orow[dcb * 16 + l15] = acc[dcb][r] * invr;
    }
}

// ---------------- fallback (R1 kernel, used if ws too small) ----------------
constexpr int QBF = 64;
__global__ __launch_bounds__(256) void fattn_fb(
    const float* __restrict__ Q, const float* __restrict__ K,
    const float* __restrict__ V, const float* __restrict__ scale_p,
    float* __restrict__ O)
{
    __shared__ __align__(16) char smem[32 * 1024];
    const int tid  = threadIdx.x;
    const int lane = tid & 63;
    const int wid  = tid >> 6;
    const int l15  = lane & 15;
    const int lgr  = lane >> 4;
    const int qtile = blockIdx.x;
    const int bh    = blockIdx.y;
    char* kh_b = smem;
    char* kl_b = smem + 8192;
    char* vt_b = smem + 16384;
    char* p_b  = smem + 24576 + wid * 2048;
    const float invs = 1.0f / scale_p[0];
    const int q0 = qtile * QBF + wid * 16;
    bf16x8 qh[2], ql[2];
    {
        const float* qrow = Q + ((size_t)bh * Sn + q0 + l15) * Dn;
#pragma unroll
        for (int ks = 0; ks < 2; ++ks) {
            const int d0 = ks * 32 + lgr * 8;
            f32x4 a = *(const f32x4*)(qrow + d0);
            f32x4 b = *(const f32x4*)(qrow + d0 + 4);
#pragma unroll
            for (int j = 0; j < 8; ++j) {
                float x = ((j < 4) ? a[j] : b[j - 4]) * invs;
                short h = f2bf(x);
                qh[ks][j] = h;
                ql[ks][j] = f2bf(x - bf2f(h));
            }
        }
    }
    f32x4 acc[4];
    float m_r[4], l_r[4];
#pragma unroll
    for (int i = 0; i < 4; ++i) {
        acc[i] = f32x4{0.f, 0.f, 0.f, 0.f};
        m_r[i] = -1e30f; l_r[i] = 0.f;
    }
    for (int kt = 0; kt < NT; ++kt) {
        const int k0 = kt * KB;
#pragma unroll
        for (int it = 0; it < 2; ++it) {
            const int c = tid + it * 256;
            const int row = c >> 3;
            const int d0  = (c & 7) * 8;
            const float* gk = K + ((size_t)bh * Sn + k0 + row) * Dn + d0;
            f32x4 a = *(const f32x4*)gk;
            f32x4 b = *(const f32x4*)(gk + 4);
            bf16x8 hv, lv;
#pragma unroll
            for (int j = 0; j < 8; ++j) {
                float x = (j < 4) ? a[j] : b[j - 4];
                short h = f2bf(x);
                hv[j] = h; lv[j] = f2bf(x - bf2f(h));
            }
            const int off = (d0 * 2) ^ ((row & 7) << 4);
            *(bf16x8*)(kh_b + row * 128 + off) = hv;
            *(bf16x8*)(kl_b + row * 128 + off) = lv;
        }
#pragma unroll
        for (int it = 0; it < 2; ++it) {
            const int c = tid + it * 256;
            const int d  = c >> 3;
            const int kc = c & 7;
            const float* gv = V + ((size_t)bh * Sn + k0 + kc * 8) * Dn + d;
            bf16x8 hv;
#pragma unroll
            for (int j = 0; j < 8; ++j) hv[j] = f2bf(gv[j * Dn]);
            const int off = (kc * 16) ^ ((d & 7) << 4);
            *(bf16x8*)(vt_b + d * 128 + off) = hv;
        }
        __syncthreads();
        f32x4 sc[4];
#pragma unroll
        for (int cb = 0; cb < 4; ++cb) sc[cb] = f32x4{0.f, 0.f, 0.f, 0.f};
#pragma unroll
        for (int ks = 0; ks < 2; ++ks) {
            const int koff = (ks * 32 + lgr * 8) * 2;
#pragma unroll
            for (int cb = 0; cb < 4; ++cb) {
                const int key = cb * 16 + l15;
                const int off = koff ^ ((key & 7) << 4);
                bf16x8 kbh = *(const bf16x8*)(kh_b + key * 128 + off);
                bf16x8 kbl = *(const bf16x8*)(kl_b + key * 128 + off);
                sc[cb] = MFMA16(qh[ks], kbh, sc[cb]);
                sc[cb] = MFMA16(ql[ks], kbh, sc[cb]);
                sc[cb] = MFMA16(qh[ks], kbl, sc[cb]);
            }
        }
#pragma unroll
        for (int r = 0; r < 4; ++r) {
            float mx = fmaxf(fmaxf(sc[0][r], sc[1][r]), fmaxf(sc[2][r], sc[3][r]));
#pragma unroll
            for (int msk = 1; msk < 16; msk <<= 1)
                mx = fmaxf(mx, __shfl_xor(mx, msk));
            const float mnew = fmaxf(m_r[r], mx);
            const float fac  = __expf(m_r[r] - mnew);
            m_r[r] = mnew;
            const int prow = lgr * 4 + r;
            const int pswz = (prow & 7) << 4;
            char* prowp = p_b + prow * 128;
            float rsum = 0.f;
#pragma unroll
            for (int cb = 0; cb < 4; ++cb) {
                float p = __expf(sc[cb][r] - mnew);
                short pb = f2bf(p);
                rsum += bf2f(pb);
                const int colb = (cb * 16 + l15) * 2;
                *(short*)(prowp + (colb ^ pswz)) = pb;
            }
#pragma unroll
            for (int msk = 1; msk < 16; msk <<= 1)
                rsum += __shfl_xor(rsum, msk);
            l_r[r] = l_r[r] * fac + rsum;
#pragma unroll
            for (int dcb = 0; dcb < 4; ++dcb) acc[dcb][r] *= fac;
        }
#pragma unroll
        for (int kc = 0; kc < 2; ++kc) {
            const int poff = ((kc * 32 + lgr * 8) * 2) ^ ((l15 & 7) << 4);
            bf16x8 pa = *(const bf16x8*)(p_b + l15 * 128 + poff);
            const int koff2 = (kc * 32 + lgr * 8) * 2;
#pragma unroll
            for (int dcb = 0; dcb < 4; ++dcb) {
                const int vrow = dcb * 16 + l15;
                const int voff = koff2 ^ ((vrow & 7) << 4);
                bf16x8 vb = *(const bf16x8*)(vt_b + vrow * 128 + voff);
                acc[dcb] = MFMA16(pa, vb, acc[dcb]);
            }
        }
        __syncthreads();
    }
#pragma unroll
    for (int r = 0; r < 4; ++r) {
        const int qrow = q0 + lgr * 4 + r;
        const float inv_l = 1.0f / l_r[r];
        float* orow = O + ((size_t)bh * Sn + qrow) * Dn;
#pragma unroll
        for (int dcb = 0; dcb < 4; ++dcb)
            orow[dcb * 16 + l15] = acc[dcb][r] * inv_l;
    }
}

extern "C" void kernel_launch(void* const* d_in, const int* in_sizes, int n_in,
                              void* d_out, int out_size, void* d_ws, size_t ws_size,
                              hipStream_t stream) {
    const float* Q = (const float*)d_in[0];
    const float* K = (const float*)d_in[1];
    const float* V = (const float*)d_in[2];
    const float* scale_p = (const float*)d_in[3];
    float* O = (float*)d_out;

    if (ws_size >= WS_NEED) {
        char* kh_g = (char*)d_ws;
        char* kl_g = kh_g + ARR_B;
        char* vt_g = kl_g + ARR_B;
        dim3 pgrid(NT, BH);
        prep<<<pgrid, 256, 0, stream>>>(K, V, kh_g, kl_g, vt_g);
        dim3 grid(Sn / QB, BH);   // 16 x 32 = 512 blocks, 512 threads
        fattn3<<<grid, 512, 0, stream>>>(Q, kh_g, kl_g, vt_g, scale_p, O);
    } else {
        dim3 grid(Sn / QBF, BH);
        fattn_fb<<<grid, 256, 0, stream>>>(Q, K, V, scale_p, O);
    }
}

// Round 4
// 79.459 us; speedup vs baseline: 2.2497x; 1.2280x over previous
//
#include <hip/hip_runtime.h>
#include <hip/hip_bf16.h>

// SDPA forward: out = softmax(Q K^T / scale) V ; B=2,H=16,S=2048,D=64, fp32 io.
// R4: f16 compute (error budget: QK f16 ~1e-4, PV f16 ~3e-4 << 8.16e-3 threshold),
// mfma_f32_32x32x16_f16, 32 q/wave (4 waves, QB=128). Swapped QK (S^T lane-local
// per q). P stays IN REGISTER: cvt_pkrtz + v_permlane32_swap_b32 build the PV
// B-fragment (T12). Pre-pass writes swizzled f16 K / V^T tile images to d_ws;
// main kernel stages via global_load_lds + 2-phase double buffer.

typedef __attribute__((ext_vector_type(8))) _Float16 f16x8;
typedef __attribute__((ext_vector_type(2))) _Float16 f16x2;
typedef __attribute__((ext_vector_type(8))) short bf16x8;
typedef __attribute__((ext_vector_type(4))) float f32x4;
typedef __attribute__((ext_vector_type(16))) float f32x16;
typedef __attribute__((address_space(3))) unsigned int lds_u32;
typedef __attribute__((address_space(1))) const unsigned int glb_u32;

#define MFMA32(a, b, c) __builtin_amdgcn_mfma_f32_32x32x16_f16((a), (b), (c), 0, 0, 0)
#define MFMA16(a, b, c) __builtin_amdgcn_mfma_f32_16x16x32_bf16((a), (b), (c), 0, 0, 0)

constexpr int Sn = 2048;
constexpr int Dn = 64;
constexpr int QB = 128;  // 4 waves x 32 q
constexpr int KB = 64;   // keys per tile
constexpr int BH = 32;   // B*H
constexpr int NT = Sn / KB;              // 32 k-tiles
constexpr size_t TILE_B = 8192;          // 64x64 f16 tile image
constexpr size_t ARR_B  = (size_t)BH * NT * TILE_B;   // 8 MB per array
constexpr size_t WS_NEED = 2 * ARR_B;                 // 16 MB

__device__ __forceinline__ short f2bf(float x) {
    unsigned u = __builtin_bit_cast(unsigned, x);
    unsigned r = u + 0x7fffu + ((u >> 16) & 1u);
    return (short)(r >> 16);
}
__device__ __forceinline__ float bf2f(short h) {
    unsigned u = ((unsigned)(unsigned short)h) << 16;
    return __builtin_bit_cast(float, u);
}

// ---------------- pre-pass: swizzled f16 tile images (K and V^T) ----------------
__global__ __launch_bounds__(256) void prep(
    const float* __restrict__ K, const float* __restrict__ V,
    char* __restrict__ k_g, char* __restrict__ v_g)
{
    const int tid = threadIdx.x;
    const int kt  = blockIdx.x;
    const int bh  = blockIdx.y;
    const int k0  = kt * KB;
    const size_t tbase = ((size_t)bh * NT + kt) * TILE_B;

    // K rows [key][d], XOR-swizzled
#pragma unroll
    for (int it = 0; it < 2; ++it) {
        const int c   = tid + it * 256;
        const int row = c >> 3;
        const int d0  = (c & 7) * 8;
        const float* gk = K + ((size_t)bh * Sn + k0 + row) * Dn + d0;
        f32x4 a = *(const f32x4*)gk;
        f32x4 b = *(const f32x4*)(gk + 4);
        f16x8 hv;
#pragma unroll
        for (int j = 0; j < 8; ++j) hv[j] = (_Float16)((j < 4) ? a[j] : b[j - 4]);
        *(f16x8*)(k_g + tbase + row * 128 + ((d0 * 2) ^ ((row & 7) << 4))) = hv;
    }
    // V^T rows [d][key], XOR-swizzled (transpose paid once)
#pragma unroll
    for (int it = 0; it < 2; ++it) {
        const int c  = tid + it * 256;
        const int d  = c >> 3;
        const int kc = c & 7;
        const float* gv = V + ((size_t)bh * Sn + k0 + kc * 8) * Dn + d;
        f16x8 hv;
#pragma unroll
        for (int j = 0; j < 8; ++j) hv[j] = (_Float16)gv[j * Dn];
        *(f16x8*)(v_g + tbase + d * 128 + ((kc * 16) ^ ((d & 7) << 4))) = hv;
    }
}

// ---------------- main flash kernel (256 threads, 4 waves x 32 q) ----------------
__device__ __forceinline__ void stage8(const char* g, char* l, int wid, int lane) {
    // 8KB: 2 rounds x 4 waves x 64 lanes x 16B (linear dest; source pre-swizzled)
#pragma unroll
    for (int r2 = 0; r2 < 2; ++r2) {
        const int off = r2 * 4096 + wid * 1024;
        __builtin_amdgcn_global_load_lds((glb_u32*)(g + off + lane * 16),
                                         (lds_u32*)(l + off), 16, 0, 0);
    }
}

__global__ __launch_bounds__(256, 2) void fattn4(
    const float* __restrict__ Q,
    const char* __restrict__ k_g, const char* __restrict__ v_g,
    const float* __restrict__ scale_p, float* __restrict__ O)
{
    // LDS: 2 buffers x (K 8K | Vt 8K) = 32K. No P buffer.
    __shared__ __align__(16) char smem[32 * 1024];

    const int tid  = threadIdx.x;
    const int lane = tid & 63;
    const int wid  = tid >> 6;          // 0..3
    const int l31  = lane & 31;
    const int h    = lane >> 5;         // 0/1
    const int qtile = blockIdx.x;
    const int bh    = blockIdx.y;

    const char* kg = k_g + (size_t)bh * NT * TILE_B;
    const char* vg = v_g + (size_t)bh * NT * TILE_B;

    // fold log2(e)/scale into Q -> softmax in exp2 domain
    const float cscale = 1.4426950408889634f / scale_p[0];

    // Q B-fragments: lane = col q = l31; k(d) = 16*ks + 8*h + j
    const int q = qtile * QB + wid * 32 + l31;
    f16x8 qf[4];
    {
        const float* qrow = Q + ((size_t)bh * Sn + q) * Dn;
#pragma unroll
        for (int ks = 0; ks < 4; ++ks) {
            const float* p = qrow + ks * 16 + h * 8;
            f32x4 a = *(const f32x4*)p;
            f32x4 b = *(const f32x4*)(p + 4);
#pragma unroll
            for (int j = 0; j < 8; ++j)
                qf[ks][j] = (_Float16)((((j < 4) ? a[j] : b[j - 4])) * cscale);
        }
    }

    f32x16 acc0, acc1;     // O^T[d][q]: d-tiles 0 (d 0-31) and 1 (d 32-63)
#pragma unroll
    for (int r = 0; r < 16; ++r) { acc0[r] = 0.f; acc1[r] = 0.f; }
    float m1 = -1e30f, l1 = 0.f;   // per-q (lane-local) running stats

    const int swz = (l31 & 7) << 4;

    // prologue: stage tile 0
    stage8(kg, smem + 0,    wid, lane);
    stage8(vg, smem + 8192, wid, lane);
    asm volatile("s_waitcnt vmcnt(0)" ::: "memory");
    __syncthreads();

    int cur = 0;
    for (int kt = 0; kt < NT; ++kt) {
        if (kt + 1 < NT) {
            char* nb = smem + (cur ^ 1) * 16384;
            const size_t toff = (size_t)(kt + 1) * TILE_B;
            stage8(kg + toff, nb,        wid, lane);
            stage8(vg + toff, nb + 8192, wid, lane);
        }
        const char* kb = smem + cur * 16384;
        const char* vb = kb + 8192;

        // ---- QK^T (swapped): S^T[key][q], A = K rows, B = Q ----
        f32x16 s0, s1;
#pragma unroll
        for (int r = 0; r < 16; ++r) { s0[r] = 0.f; s1[r] = 0.f; }
        __builtin_amdgcn_s_setprio(1);
#pragma unroll
        for (int ks = 0; ks < 4; ++ks) {
            const int boff = (32 * ks + 16 * h) ^ swz;
            f16x8 k0f = *(const f16x8*)(kb + l31 * 128 + boff);
            f16x8 k1f = *(const f16x8*)(kb + (l31 + 32) * 128 + boff);
            s0 = MFMA32(k0f, qf[ks], s0);
            s1 = MFMA32(k1f, qf[ks], s1);
        }
        __builtin_amdgcn_s_setprio(0);

        // ---- lane-local softmax: lane holds 32 scores for q = l31 ----
        float mr[16];
#pragma unroll
        for (int i = 0; i < 16; ++i) mr[i] = fmaxf(s0[i], s1[i]);
#pragma unroll
        for (int st = 8; st > 0; st >>= 1)
#pragma unroll
            for (int i = 0; i < st; ++i) mr[i] = fmaxf(mr[i], mr[i + st]);
        const float mx = fmaxf(mr[0], __shfl_xor(mr[0], 32));

        // T13 defer-rescale (THR=4 -> p bounded by 16, f16-safe)
        if (__any(mx > m1 + 4.0f)) {
            const float mnew = fmaxf(m1, mx);
            const float fac  = exp2f(m1 - mnew);
            m1 = mnew;
            l1 *= fac;
#pragma unroll
            for (int r = 0; r < 16; ++r) { acc0[r] *= fac; acc1[r] *= fac; }
        }

        // p = exp2(s - m1) in place; f32 tree-sum for denominator
#pragma unroll
        for (int r = 0; r < 16; ++r) { s0[r] = exp2f(s0[r] - m1); s1[r] = exp2f(s1[r] - m1); }
        float sr[16];
#pragma unroll
        for (int i = 0; i < 16; ++i) sr[i] = s0[i] + s1[i];
#pragma unroll
        for (int st = 8; st > 0; st >>= 1)
#pragma unroll
            for (int i = 0; i < st; ++i) sr[i] += sr[i + st];
        l1 += sr[0] + __shfl_xor(sr[0], 32);

        // ---- PV: per k-step build P B-frag in-register (cvt_pkrtz + permlane32_swap) ----
        __builtin_amdgcn_s_setprio(1);
#pragma unroll
        for (int s = 0; s < 4; ++s) {
            const f32x16& P = (s & 2) ? s1 : s0;   // key-tile t = s>>1
            const int rb = (s & 1) * 8;            // reg base within tile
            unsigned wA0 = __builtin_bit_cast(unsigned, __builtin_amdgcn_cvt_pkrtz(P[rb + 0], P[rb + 1]));
            unsigned wA1 = __builtin_bit_cast(unsigned, __builtin_amdgcn_cvt_pkrtz(P[rb + 2], P[rb + 3]));
            unsigned wB0 = __builtin_bit_cast(unsigned, __builtin_amdgcn_cvt_pkrtz(P[rb + 4], P[rb + 5]));
            unsigned wB1 = __builtin_bit_cast(unsigned, __builtin_amdgcn_cvt_pkrtz(P[rb + 6], P[rb + 7]));
            // lo lane gets partner keys +4..7 ; hi lane gets partner keys +8..11
            asm("v_permlane32_swap_b32 %0, %1" : "+v"(wA0), "+v"(wB0));
            asm("v_permlane32_swap_b32 %0, %1" : "+v"(wA1), "+v"(wB1));
            union { f16x8 v; unsigned u[4]; } pf;
            pf.u[0] = wA0; pf.u[1] = wA1; pf.u[2] = wB0; pf.u[3] = wB1;

            const int boff = (32 * s + 16 * h) ^ swz;
            f16x8 v0 = *(const f16x8*)(vb + l31 * 128 + boff);
            f16x8 v1 = *(const f16x8*)(vb + (l31 + 32) * 128 + boff);
            acc0 = MFMA32(v0, pf.v, acc0);
            acc1 = MFMA32(v1, pf.v, acc1);
        }
        __builtin_amdgcn_s_setprio(0);

        asm volatile("s_waitcnt vmcnt(0)" ::: "memory");
        __syncthreads();
        cur ^= 1;
    }

    // ---- epilogue: O[q][d] = acc/l1 ; d = (r&3) + 8*(r>>2) + 4h (+32 for tile 1) ----
    const float invl = 1.0f / l1;
    float* orow = O + ((size_t)bh * Sn + q) * Dn;
#pragma unroll
    for (int g = 0; g < 4; ++g) {
        f32x4 o0, o1;
#pragma unroll
        for (int i = 0; i < 4; ++i) {
            o0[i] = acc0[g * 4 + i] * invl;
            o1[i] = acc1[g * 4 + i] * invl;
        }
        *(f32x4*)(orow + 8 * g + 4 * h)      = o0;
        *(f32x4*)(orow + 32 + 8 * g + 4 * h) = o1;
    }
}

// ---------------- fallback (self-contained bf16, used if ws too small) ----------------
constexpr int QBF = 64;
__global__ __launch_bounds__(256) void fattn_fb(
    const float* __restrict__ Q, const float* __restrict__ K,
    const float* __restrict__ V, const float* __restrict__ scale_p,
    float* __restrict__ O)
{
    __shared__ __align__(16) char smem[32 * 1024];
    const int tid  = threadIdx.x;
    const int lane = tid & 63;
    const int wid  = tid >> 6;
    const int l15  = lane & 15;
    const int lgr  = lane >> 4;
    const int qtile = blockIdx.x;
    const int bh    = blockIdx.y;
    char* kh_b = smem;
    char* kl_b = smem + 8192;
    char* vt_b = smem + 16384;
    char* p_b  = smem + 24576 + wid * 2048;
    const float invs = 1.0f / scale_p[0];
    const int q0 = qtile * QBF + wid * 16;
    bf16x8 qh[2], ql[2];
    {
        const float* qrow = Q + ((size_t)bh * Sn + q0 + l15) * Dn;
#pragma unroll
        for (int ks = 0; ks < 2; ++ks) {
            const int d0 = ks * 32 + lgr * 8;
            f32x4 a = *(const f32x4*)(qrow + d0);
            f32x4 b = *(const f32x4*)(qrow + d0 + 4);
#pragma unroll
            for (int j = 0; j < 8; ++j) {
                float x = ((j < 4) ? a[j] : b[j - 4]) * invs;
                short hh = f2bf(x);
                qh[ks][j] = hh;
                ql[ks][j] = f2bf(x - bf2f(hh));
            }
        }
    }
    f32x4 acc[4];
    float m_r[4], l_r[4];
#pragma unroll
    for (int i = 0; i < 4; ++i) {
        acc[i] = f32x4{0.f, 0.f, 0.f, 0.f};
        m_r[i] = -1e30f; l_r[i] = 0.f;
    }
    for (int kt = 0; kt < NT; ++kt) {
        const int k0 = kt * KB;
#pragma unroll
        for (int it = 0; it < 2; ++it) {
            const int c = tid + it * 256;
            const int row = c >> 3;
            const int d0  = (c & 7) * 8;
            const float* gk = K + ((size_t)bh * Sn + k0 + row) * Dn + d0;
            f32x4 a = *(const f32x4*)gk;
            f32x4 b = *(const f32x4*)(gk + 4);
            bf16x8 hv, lv;
#pragma unroll
            for (int j = 0; j < 8; ++j) {
                float x = (j < 4) ? a[j] : b[j - 4];
                short hh = f2bf(x);
                hv[j] = hh; lv[j] = f2bf(x - bf2f(hh));
            }
            const int off = (d0 * 2) ^ ((row & 7) << 4);
            *(bf16x8*)(kh_b + row * 128 + off) = hv;
            *(bf16x8*)(kl_b + row * 128 + off) = lv;
        }
#pragma unroll
        for (int it = 0; it < 2; ++it) {
            const int c = tid + it * 256;
            const int d  = c >> 3;
            const int kc = c & 7;
            const float* gv = V + ((size_t)bh * Sn + k0 + kc * 8) * Dn + d;
            bf16x8 hv;
#pragma unroll
            for (int j = 0; j < 8; ++j) hv[j] = f2bf(gv[j * Dn]);
            const int off = (kc * 16) ^ ((d & 7) << 4);
            *(bf16x8*)(vt_b + d * 128 + off) = hv;
        }
        __syncthreads();
        f32x4 sc[4];
#pragma unroll
        for (int cb = 0; cb < 4; ++cb) sc[cb] = f32x4{0.f, 0.f, 0.f, 0.f};
#pragma unroll
        for (int ks = 0; ks < 2; ++ks) {
            const int koff = (ks * 32 + lgr * 8) * 2;
#pragma unroll
            for (int cb = 0; cb < 4; ++cb) {
                const int key = cb * 16 + l15;
                const int off = koff ^ ((key & 7) << 4);
                bf16x8 kbh = *(const bf16x8*)(kh_b + key * 128 + off);
                bf16x8 kbl = *(const bf16x8*)(kl_b + key * 128 + off);
                sc[cb] = MFMA16(qh[ks], kbh, sc[cb]);
                sc[cb] = MFMA16(ql[ks], kbh, sc[cb]);
                sc[cb] = MFMA16(qh[ks], kbl, sc[cb]);
            }
        }
#pragma unroll
        for (int r = 0; r < 4; ++r) {
            float mx = fmaxf(fmaxf(sc[0][r], sc[1][r]), fmaxf(sc[2][r], sc[3][r]));
#pragma unroll
            for (int msk = 1; msk < 16; msk <<= 1)
                mx = fmaxf(mx, __shfl_xor(mx, msk));
            const float mnew = fmaxf(m_r[r], mx);
            const float fac  = __expf(m_r[r] - mnew);
            m_r[r] = mnew;
            const int prow = lgr * 4 + r;
            const int pswz = (prow & 7) << 4;
            char* prowp = p_b + prow * 128;
            float rsum = 0.f;
#pragma unroll
            for (int cb = 0; cb < 4; ++cb) {
                float p = __expf(sc[cb][r] - mnew);
                short pb = f2bf(p);
                rsum += bf2f(pb);
                const int colb = (cb * 16 + l15) * 2;
                *(short*)(prowp + (colb ^ pswz)) = pb;
            }
#pragma unroll
            for (int msk = 1; msk < 16; msk <<= 1)
                rsum += __shfl_xor(rsum, msk);
            l_r[r] = l_r[r] * fac + rsum;
#pragma unroll
            for (int dcb = 0; dcb < 4; ++dcb) acc[dcb][r] *= fac;
        }
#pragma unroll
        for (int kc = 0; kc < 2; ++kc) {
            const int poff = ((kc * 32 + lgr * 8) * 2) ^ ((l15 & 7) << 4);
            bf16x8 pa = *(const bf16x8*)(p_b + l15 * 128 + poff);
            const int koff2 = (kc * 32 + lgr * 8) * 2;
#pragma unroll
            for (int dcb = 0; dcb < 4; ++dcb) {
                const int vrow = dcb * 16 + l15;
                const int voff = koff2 ^ ((vrow & 7) << 4);
                bf16x8 vb = *(const bf16x8*)(vt_b + vrow * 128 + voff);
                acc[dcb] = MFMA16(pa, vb, acc[dcb]);
            }
        }
        __syncthreads();
    }
#pragma unroll
    for (int r = 0; r < 4; ++r) {
        const int qrow = q0 + lgr * 4 + r;
        const float inv_l = 1.0f / l_r[r];
        float* orow = O + ((size_t)bh * Sn + qrow) * Dn;
#pragma unroll
        for (int dcb = 0; dcb < 4; ++dcb)
            orow[dcb * 16 + l15] = acc[dcb][r] * inv_l;
    }
}

extern "C" void kernel_launch(void* const* d_in, const int* in_sizes, int n_in,
                              void* d_out, int out_size, void* d_ws, size_t ws_size,
                              hipStream_t stream) {
    const float* Q = (const float*)d_in[0];
    const float* K = (const float*)d_in[1];
    const float* V = (const float*)d_in[2];
    const float* scale_p = (const float*)d_in[3];
    float* O = (float*)d_out;

    if (ws_size >= WS_NEED) {
        char* k_g = (char*)d_ws;
        char* v_g = k_g + ARR_B;
        dim3 pgrid(NT, BH);
        prep<<<pgrid, 256, 0, stream>>>(K, V, k_g, v_g);
        dim3 grid(Sn / QB, BH);   // 16 x 32 = 512 blocks, 256 threads
        fattn4<<<grid, 256, 0, stream>>>(Q, k_g, v_g, scale_p, O);
    } else {
        dim3 grid(Sn / QBF, BH);
        fattn_fb<<<grid, 256, 0, stream>>>(Q, K, V, scale_p, O);
    }
}